// Round 2
// baseline (562.221 us; speedup 1.0000x reference)
//
#include <hip/hip_runtime.h>

#define D_DIM 2048
#define K_DIM 64
#define T_DIM 2048
#define BT_DIM 16384   // B*T = 8*2048

// ---------------------------------------------------------------------------
// Kernel A: softmax over k of w[d,:], stored TRANSPOSED: pT[k,d].
// One wave per d row (lane = k).
// ---------------------------------------------------------------------------
__global__ __launch_bounds__(256) void softmax_k(const float* __restrict__ w,
                                                 float* __restrict__ pT) {
    const int lane = threadIdx.x & 63;
    const int d = blockIdx.x * 4 + (threadIdx.x >> 6);
    float v = w[d * K_DIM + lane];
    float m = v;
#pragma unroll
    for (int off = 32; off > 0; off >>= 1) m = fmaxf(m, __shfl_xor(m, off, 64));
    float e = expf(v - m);
    float s = e;
#pragma unroll
    for (int off = 32; off > 0; off >>= 1) s += __shfl_xor(s, off, 64);
    pT[(size_t)lane * D_DIM + d] = e / s;   // transposed store (tiny kernel, OK)
}

// ---------------------------------------------------------------------------
// Kernel B: per-column min/max of w, then nT[k,d] = (w[d,k]-mn)/(mx-mn).
// One block per k column.
// ---------------------------------------------------------------------------
__global__ __launch_bounds__(256) void norm_k(const float* __restrict__ w,
                                              float* __restrict__ nT) {
    const int k = blockIdx.x;
    const int lane = threadIdx.x & 63;
    const int wave = threadIdx.x >> 6;
    float mn = 1e30f, mx = -1e30f;
    for (int d = threadIdx.x; d < D_DIM; d += 256) {
        float v = w[d * K_DIM + k];
        mn = fminf(mn, v);
        mx = fmaxf(mx, v);
    }
#pragma unroll
    for (int off = 32; off > 0; off >>= 1) {
        mn = fminf(mn, __shfl_xor(mn, off, 64));
        mx = fmaxf(mx, __shfl_xor(mx, off, 64));
    }
    __shared__ float red[8];
    if (lane == 0) { red[wave] = mn; red[4 + wave] = mx; }
    __syncthreads();
    mn = fminf(fminf(red[0], red[1]), fminf(red[2], red[3]));
    mx = fmaxf(fmaxf(red[4], red[5]), fmaxf(red[6], red[7]));
    const float inv = 1.0f / (mx - mn);
    for (int d = threadIdx.x; d < D_DIM; d += 256) {
        nT[k * D_DIM + d] = (w[d * K_DIM + k] - mn) * inv;
    }
}

// ---------------------------------------------------------------------------
// Kernel C1: scores = X @ P (fp32 VALU) -> per-row (argmax, sign).
// One block per 16 rows; the 4 waves split D (512 each), lane = k.
// Partials reduced through LDS; stats[r] = ind | neg<<8.
// ---------------------------------------------------------------------------
__global__ __launch_bounds__(256, 4) void gemm_stats_k(const float* __restrict__ x,
                                                       const float* __restrict__ pT,
                                                       int* __restrict__ stats) {
    const int lane = threadIdx.x & 63;
    const int wave = threadIdx.x >> 6;
    const int r0 = blockIdx.x * 16;
    const int d0 = wave * (D_DIM / 4);

    float acc[16];
#pragma unroll
    for (int r = 0; r < 16; ++r) acc[r] = 0.0f;

    const float* xbase = x + (size_t)r0 * D_DIM + d0;
    const float* pbase = pT + (size_t)lane * D_DIM + d0;   // lane = k

    for (int d4 = 0; d4 < D_DIM / 4; d4 += 4) {
        const float4 pv = *(const float4*)(pbase + d4);    // L2-resident
#pragma unroll
        for (int r = 0; r < 16; ++r) {
            const float4 xv = *(const float4*)(xbase + (size_t)r * D_DIM + d4);
            float a = acc[r];
            a = fmaf(xv.x, pv.x, a);
            a = fmaf(xv.y, pv.y, a);
            a = fmaf(xv.z, pv.z, a);
            a = fmaf(xv.w, pv.w, a);
            acc[r] = a;
        }
    }

    // cross-wave reduction: red[wave][r][k], lane-contiguous => conflict-free
    __shared__ float red[4][16][64];
#pragma unroll
    for (int r = 0; r < 16; ++r) red[wave][r][lane] = acc[r];
    __syncthreads();

    // wave w finalizes rows [4w, 4w+4)
#pragma unroll
    for (int rr = 0; rr < 4; ++rr) {
        const int r = wave * 4 + rr;
        float v = red[0][r][lane] + red[1][r][lane] + red[2][r][lane] + red[3][r][lane];
        int idx = lane;
#pragma unroll
        for (int off = 32; off > 0; off >>= 1) {
            const float ov = __shfl_xor(v, off, 64);
            const int oi = __shfl_xor(idx, off, 64);
            if (ov > v || (ov == v && oi < idx)) { v = ov; idx = oi; }
        }
        if (lane == 0) stats[r0 + r] = idx | ((v < 0.0f) ? (1 << 8) : 0);
    }
}

// ---------------------------------------------------------------------------
// Kernel C2: out[r,d] = x[r,d] * (1 + W), W from stats[r-1]; rows t==0: W=0.
// One block per row, float4 vectorized.
// ---------------------------------------------------------------------------
__global__ __launch_bounds__(256) void output_k(const float* __restrict__ x,
                                                const float* __restrict__ nT,
                                                const int* __restrict__ stats,
                                                float* __restrict__ out) {
    const int row = blockIdx.x;
    const int t = row & (T_DIM - 1);
    const float4* x4 = (const float4*)(x + (size_t)row * D_DIM);
    float4* o4 = (float4*)(out + (size_t)row * D_DIM);
    if (t == 0) {
#pragma unroll
        for (int it = 0; it < 2; ++it) {
            const int i = threadIdx.x + it * 256;
            o4[i] = x4[i];
        }
        return;
    }
    const int s = stats[row - 1];
    const int ind = s & 0xff;
    const bool neg = (s >> 8) & 1;
    const float4* n4 = (const float4*)(nT + (size_t)ind * D_DIM);
#pragma unroll
    for (int it = 0; it < 2; ++it) {
        const int i = threadIdx.x + it * 256;
        const float4 xv = x4[i];
        const float4 nv = n4[i];
        float4 r;
        const float w0 = neg ? 1.0f - nv.x : nv.x;
        const float w1 = neg ? 1.0f - nv.y : nv.y;
        const float w2 = neg ? 1.0f - nv.z : nv.z;
        const float w3 = neg ? 1.0f - nv.w : nv.w;
        r.x = fmaf(xv.x, w0, xv.x);
        r.y = fmaf(xv.y, w1, xv.y);
        r.z = fmaf(xv.z, w2, xv.z);
        r.w = fmaf(xv.w, w3, xv.w);
        o4[i] = r;
    }
}

extern "C" void kernel_launch(void* const* d_in, const int* in_sizes, int n_in,
                              void* d_out, int out_size, void* d_ws, size_t ws_size,
                              hipStream_t stream) {
    const float* x = (const float*)d_in[0];   // [B,T,D] fp32
    const float* w = (const float*)d_in[1];   // [D,K] fp32
    float* out = (float*)d_out;

    float* pT = (float*)d_ws;                 // [K,D]  512 KB (transposed softmax)
    float* nT = pT + (size_t)K_DIM * D_DIM;   // [K,D]  512 KB
    int* stats = (int*)(nT + (size_t)K_DIM * D_DIM);  // [B*T] 64 KB

    softmax_k<<<D_DIM / 4, 256, 0, stream>>>(w, pT);
    norm_k<<<K_DIM, 256, 0, stream>>>(w, nT);
    gemm_stats_k<<<BT_DIM / 16, 256, 0, stream>>>(x, pT, stats);
    output_k<<<BT_DIM, 256, 0, stream>>>(x, nT, stats, out);
}

// Round 3
// 371.415 us; speedup vs baseline: 1.5137x; 1.5137x over previous
//
#include <hip/hip_runtime.h>
#include <stdint.h>

#define D_DIM 2048
#define K_DIM 64
#define T_DIM 2048
#define BT_DIM 16384   // B*T = 8*2048

typedef __attribute__((address_space(3))) uint32_t lds_u32;
typedef const __attribute__((address_space(1))) uint32_t glob_u32;

// ---------------------------------------------------------------------------
// Kernel A: softmax over k of w[d,:], stored TRANSPOSED: pT[k,d].
// ---------------------------------------------------------------------------
__global__ __launch_bounds__(256) void softmax_k(const float* __restrict__ w,
                                                 float* __restrict__ pT) {
    const int lane = threadIdx.x & 63;
    const int d = blockIdx.x * 4 + (threadIdx.x >> 6);
    float v = w[d * K_DIM + lane];
    float m = v;
#pragma unroll
    for (int off = 32; off > 0; off >>= 1) m = fmaxf(m, __shfl_xor(m, off, 64));
    float e = expf(v - m);
    float s = e;
#pragma unroll
    for (int off = 32; off > 0; off >>= 1) s += __shfl_xor(s, off, 64);
    pT[(size_t)lane * D_DIM + d] = e / s;
}

// ---------------------------------------------------------------------------
// Kernel B: per-column min/max of w -> nT[k,d] = (w[d,k]-mn)/(mx-mn).
// ---------------------------------------------------------------------------
__global__ __launch_bounds__(256) void norm_k(const float* __restrict__ w,
                                              float* __restrict__ nT) {
    const int k = blockIdx.x;
    const int lane = threadIdx.x & 63;
    const int wave = threadIdx.x >> 6;
    float mn = 1e30f, mx = -1e30f;
    for (int d = threadIdx.x; d < D_DIM; d += 256) {
        float v = w[d * K_DIM + k];
        mn = fminf(mn, v);
        mx = fmaxf(mx, v);
    }
#pragma unroll
    for (int off = 32; off > 0; off >>= 1) {
        mn = fminf(mn, __shfl_xor(mn, off, 64));
        mx = fmaxf(mx, __shfl_xor(mx, off, 64));
    }
    __shared__ float red[8];
    if (lane == 0) { red[wave] = mn; red[4 + wave] = mx; }
    __syncthreads();
    mn = fminf(fminf(red[0], red[1]), fminf(red[2], red[3]));
    mx = fmaxf(fmaxf(red[4], red[5]), fmaxf(red[6], red[7]));
    const float inv = 1.0f / (mx - mn);
    for (int d = threadIdx.x; d < D_DIM; d += 256) {
        nT[k * D_DIM + d] = (w[d * K_DIM + k] - mn) * inv;
    }
}

// ---------------------------------------------------------------------------
// Kernel C1: scores = X @ P (fp32 VALU) -> per-row (argmax, sign).
// Block = 16 rows; 4 waves split D into quarters of 512; lane = k.
// x corner-turned through LDS: coalesced global_load_lds (16B/lane) stage,
// then broadcast ds_read_b128 feeding 4 FMAs. p[k] rows live in VGPRs.
// Per-wave staging => only s_waitcnt vmcnt(0), no __syncthreads in K-loop.
// ---------------------------------------------------------------------------
__global__ __launch_bounds__(256, 4) void gemm_stats_k(const float* __restrict__ x,
                                                       const float* __restrict__ pT,
                                                       int* __restrict__ stats) {
    const int lane = threadIdx.x & 63;
    const int wave = threadIdx.x >> 6;
    const int r0 = blockIdx.x * 16;
    const int dw0 = wave * (D_DIM / 4);            // this wave's d-quarter

    __shared__ float xs_all[4][16][64];            // 16 KB: per-wave x tile [16 r][64 d]
    float* xs = (float*)xs_all[wave];

    float acc[16];
#pragma unroll
    for (int r = 0; r < 16; ++r) acc[r] = 0.0f;

    const float* xg = x + (size_t)r0 * D_DIM + dw0;        // wave's x panel
    const float* pg = pT + (size_t)lane * D_DIM + dw0;     // lane = k row of pT

    const int srow = lane >> 4;                    // 0..3  (staging row within group)
    const int scol = (lane & 15) * 4;              // 0,4,...,60 (staging col)

    for (int it = 0; it < 8; ++it) {
        const int d0 = it * 64;
        // ---- stage x tile [16 r][64 d]: 4 coalesced global_load_lds (1KB each)
#pragma unroll
        for (int j = 0; j < 4; ++j) {
            const float* src = xg + (size_t)(j * 4 + srow) * D_DIM + d0 + scol;
            __builtin_amdgcn_global_load_lds((glob_u32*)src,
                                             (lds_u32*)(xs + j * 256),
                                             16, 0, 0);
        }
        // ---- two 32-d halves to keep p-register pressure at 8 float4
#pragma unroll
        for (int h = 0; h < 2; ++h) {
            float4 pv[8];
#pragma unroll
            for (int j = 0; j < 8; ++j)
                pv[j] = *(const float4*)(pg + d0 + h * 32 + j * 4);
            if (h == 0) {
                // stage (4) + pv (8) all needed before compute; drain vmem.
                asm volatile("s_waitcnt vmcnt(0)" ::: "memory");
            }
#pragma unroll
            for (int r = 0; r < 16; ++r) {
                float a = acc[r];
#pragma unroll
                for (int j = 0; j < 8; ++j) {
                    const float4 xv = *(const float4*)(xs + r * 64 + h * 32 + j * 4);
                    a = fmaf(xv.x, pv[j].x, a);
                    a = fmaf(xv.y, pv[j].y, a);
                    a = fmaf(xv.z, pv[j].z, a);
                    a = fmaf(xv.w, pv[j].w, a);
                }
                acc[r] = a;
            }
        }
    }

    // ---- cross-wave reduction + 64-lane argmax (first-index tie-break)
    __shared__ float red[4][16][64];               // 16 KB
#pragma unroll
    for (int r = 0; r < 16; ++r) red[wave][r][lane] = acc[r];
    __syncthreads();

#pragma unroll
    for (int rr = 0; rr < 4; ++rr) {
        const int r = wave * 4 + rr;
        float v = red[0][r][lane] + red[1][r][lane] + red[2][r][lane] + red[3][r][lane];
        int idx = lane;
#pragma unroll
        for (int off = 32; off > 0; off >>= 1) {
            const float ov = __shfl_xor(v, off, 64);
            const int oi = __shfl_xor(idx, off, 64);
            if (ov > v || (ov == v && oi < idx)) { v = ov; idx = oi; }
        }
        if (lane == 0) stats[r0 + r] = idx | ((v < 0.0f) ? (1 << 8) : 0);
    }
}

// ---------------------------------------------------------------------------
// Kernel C2: out[r,d] = x[r,d] * (1 + W), W from stats[r-1]; rows t==0: W=0.
// ---------------------------------------------------------------------------
__global__ __launch_bounds__(256) void output_k(const float* __restrict__ x,
                                                const float* __restrict__ nT,
                                                const int* __restrict__ stats,
                                                float* __restrict__ out) {
    const int row = blockIdx.x;
    const int t = row & (T_DIM - 1);
    const float4* x4 = (const float4*)(x + (size_t)row * D_DIM);
    float4* o4 = (float4*)(out + (size_t)row * D_DIM);
    if (t == 0) {
#pragma unroll
        for (int it = 0; it < 2; ++it) {
            const int i = threadIdx.x + it * 256;
            o4[i] = x4[i];
        }
        return;
    }
    const int s = stats[row - 1];
    const int ind = s & 0xff;
    const bool neg = (s >> 8) & 1;
    const float4* n4 = (const float4*)(nT + (size_t)ind * D_DIM);
#pragma unroll
    for (int it = 0; it < 2; ++it) {
        const int i = threadIdx.x + it * 256;
        const float4 xv = x4[i];
        const float4 nv = n4[i];
        float4 r;
        const float w0 = neg ? 1.0f - nv.x : nv.x;
        const float w1 = neg ? 1.0f - nv.y : nv.y;
        const float w2 = neg ? 1.0f - nv.z : nv.z;
        const float w3 = neg ? 1.0f - nv.w : nv.w;
        r.x = fmaf(xv.x, w0, xv.x);
        r.y = fmaf(xv.y, w1, xv.y);
        r.z = fmaf(xv.z, w2, xv.z);
        r.w = fmaf(xv.w, w3, xv.w);
        o4[i] = r;
    }
}

extern "C" void kernel_launch(void* const* d_in, const int* in_sizes, int n_in,
                              void* d_out, int out_size, void* d_ws, size_t ws_size,
                              hipStream_t stream) {
    const float* x = (const float*)d_in[0];   // [B,T,D] fp32
    const float* w = (const float*)d_in[1];   // [D,K] fp32
    float* out = (float*)d_out;

    float* pT = (float*)d_ws;                 // [K,D]  512 KB (transposed softmax)
    float* nT = pT + (size_t)K_DIM * D_DIM;   // [K,D]  512 KB
    int* stats = (int*)(nT + (size_t)K_DIM * D_DIM);  // [B*T] 64 KB

    softmax_k<<<D_DIM / 4, 256, 0, stream>>>(w, pT);
    norm_k<<<K_DIM, 256, 0, stream>>>(w, nT);
    gemm_stats_k<<<BT_DIM / 16, 256, 0, stream>>>(x, pT, stats);
    output_k<<<BT_DIM, 256, 0, stream>>>(x, nT, stats, out);
}